// Round 1
// baseline (253.232 us; speedup 1.0000x reference)
//
#include <hip/hip_runtime.h>
#include <cmath>

#define R_LEVELS 16
#define N_TAB    524288u
#define N_MASK   (N_TAB - 1u)
#define PRIME_H  2654435761u
#define H_DIM    32
#define M_PTS    1048576

struct ResArr { float r[R_LEVELS]; };

__global__ __launch_bounds__(256) void ngp_fused(
    const float* __restrict__ coords,
    const float* __restrict__ hashf,
    const float* __restrict__ W0,
    const float* __restrict__ b0,
    const float* __restrict__ W1,
    const float* __restrict__ b1,
    const float* __restrict__ W2,
    const float* __restrict__ b2,
    float* __restrict__ out,
    ResArr res)
{
    const int p = blockIdx.x * blockDim.x + threadIdx.x;

    const float2 c = ((const float2*)coords)[p];

    float f[2 * R_LEVELS];

    #pragma unroll
    for (int r = 0; r < R_LEVELS; ++r) {
        const float rr = res.r[r];
        const float x = c.x * rr;
        const float y = c.y * rr;
        const float xf = floorf(x);
        const float yf = floorf(y);
        const float wx = x - xf;
        const float wy = y - yf;
        const unsigned x0 = (unsigned)xf;
        const unsigned y0 = (unsigned)yf;
        const unsigned hy0 = PRIME_H * y0;
        const unsigned hy1 = PRIME_H * (y0 + 1u);
        const unsigned i00 = (x0 ^ hy0) & N_MASK;
        const unsigned i01 = (x0 ^ hy1) & N_MASK;
        const unsigned i10 = ((x0 + 1u) ^ hy0) & N_MASK;
        const unsigned i11 = ((x0 + 1u) ^ hy1) & N_MASK;
        const float2* tab = (const float2*)hashf + (size_t)r * N_TAB;
        const float2 v00 = tab[i00];
        const float2 v01 = tab[i01];
        const float2 v10 = tab[i10];
        const float2 v11 = tab[i11];
        const float w00 = (1.f - wx) * (1.f - wy);
        const float w01 = (1.f - wx) * wy;
        const float w10 = wx * (1.f - wy);
        const float w11 = wx * wy;
        f[2*r+0] = v00.x*w00 + v01.x*w01 + v10.x*w10 + v11.x*w11;
        f[2*r+1] = v00.y*w00 + v01.y*w01 + v10.y*w10 + v11.y*w11;
    }

    // ---- layer 0: h0 = leaky(f @ W0 + b0) ----
    float h0[H_DIM];
    #pragma unroll
    for (int j = 0; j < H_DIM; ++j) h0[j] = b0[j];
    #pragma unroll
    for (int i = 0; i < H_DIM; ++i) {
        const float fi = f[i];
        #pragma unroll
        for (int j = 0; j < H_DIM; ++j)
            h0[j] = fmaf(fi, W0[i*H_DIM + j], h0[j]);
    }
    #pragma unroll
    for (int j = 0; j < H_DIM; ++j) h0[j] = fmaxf(h0[j], 0.01f * h0[j]);

    // ---- layer 1: h1 = leaky(h0 @ W1 + b1)  (reuse f[] as h1) ----
    #pragma unroll
    for (int j = 0; j < H_DIM; ++j) f[j] = b1[j];
    #pragma unroll
    for (int i = 0; i < H_DIM; ++i) {
        const float hi = h0[i];
        #pragma unroll
        for (int j = 0; j < H_DIM; ++j)
            f[j] = fmaf(hi, W1[i*H_DIM + j], f[j]);
    }
    #pragma unroll
    for (int j = 0; j < H_DIM; ++j) f[j] = fmaxf(f[j], 0.01f * f[j]);

    // ---- layer 2: o = h1 @ W2 + b2 ----
    float o0 = b2[0], o1 = b2[1], o2 = b2[2];
    #pragma unroll
    for (int i = 0; i < H_DIM; ++i) {
        const float hi = f[i];
        o0 = fmaf(hi, W2[i*3 + 0], o0);
        o1 = fmaf(hi, W2[i*3 + 1], o1);
        o2 = fmaf(hi, W2[i*3 + 2], o2);
    }

    out[(size_t)p*3 + 0] = o0;
    out[(size_t)p*3 + 1] = o1;
    out[(size_t)p*3 + 2] = o2;
}

extern "C" void kernel_launch(void* const* d_in, const int* in_sizes, int n_in,
                              void* d_out, int out_size, void* d_ws, size_t ws_size,
                              hipStream_t stream) {
    ResArr res;
    for (int i = 0; i < R_LEVELS; ++i)
        res.r[i] = (float)nearbyint(exp2(4.0 + (7.0 / 15.0) * (double)i));
    res.r[0] = 16.f;
    res.r[R_LEVELS - 1] = 2048.f;

    const float* coords = (const float*)d_in[0];
    const float* hashf  = (const float*)d_in[1];
    const float* W0     = (const float*)d_in[2];
    const float* b0     = (const float*)d_in[3];
    const float* W1     = (const float*)d_in[4];
    const float* b1     = (const float*)d_in[5];
    const float* W2     = (const float*)d_in[6];
    const float* b2     = (const float*)d_in[7];
    float* out          = (float*)d_out;

    dim3 grid(M_PTS / 256), block(256);
    hipLaunchKernelGGL(ngp_fused, grid, block, 0, stream,
                       coords, hashf, W0, b0, W1, b1, W2, b2, out, res);
}